// Round 1
// 242.407 us; speedup vs baseline: 1.0223x; 1.0223x over previous
//
#include <hip/hip_runtime.h>

// Guided filter fused kernel, round 5: K=4 vertical tile chaining.
// (16,3,512,512) fp32, r=8 (17x17 box, zero 'same' padding, analytic N).
//
// Per block: FOUR vertically stacked 32x32 output tiles (128 output rows).
// H (horizontal 17-sums of I,p,Ip,II) lives in a 64-row RING; group 0 stages
// 64 raw rows, groups 1..3 stage only 32 NEW rows -> staged/H rows per block:
// 160 vs 256 for 4 independent blocks (-37.5% of stages 1-2).
// New-row staging is overlapped with stage 5 of the previous group.
//
// LDS = exactly 80 KiB -> 2 blocks/CU (unchanged):
//   F4 : raw staging (g0: 64 rows = 32 KiB, tails: 32 rows = 16 KiB, swizzled
//        phys_granule = g ^ (row&7), halves swapped iff (row&1)). After each
//        group's stage 2, same space holds AB (48 x stride 50 float2) and
//        HAB (48 x stride 33 float2). Tail staging reuses bytes [0,16384)
//        (= AB region, dead after stage 4); HAB at byte 19200 stays live.
//   H4 : (sI,sp,sIp,sII) float4 ring [64][48], phys_col = col ^ (row&7).
// Ring slot = row&63; slot&7 == row&7 because group offsets are mult. of 32.

#define RAD  8
#define H    512
#define W    512
#define TILE 32
#define KCH  4
#define EPS  0.01f

__global__ __launch_bounds__(512, 4)
void guided_filter_kernel(const float* __restrict__ Ig,
                          const float* __restrict__ Pg,
                          float* __restrict__ out)
{
    __shared__ __align__(16) float4 F4[64 * 32];   // 32768 B
    __shared__ __align__(16) float4 H4[64 * 48];   // 49152 B (ring)

    float2* F2p = (float2*)F4;
    float2* AB  = (float2*)F4;                 // 48 rows x stride 50 (19200 B)
    float2* HAB = (float2*)F4 + 48 * 50;       // 48 rows x stride 33 (12672 B)

    const int tid   = threadIdx.x;
    const int plane = blockIdx.z;
    const int x0 = blockIdx.x * TILE - 2 * RAD;
    const int Y0 = blockIdx.y * (TILE * KCH);
    const float* Ib = Ig + (size_t)plane * (H * W);
    const float* Pb = Pg + (size_t)plane * (H * W);
    float* Ob = out + (size_t)plane * (H * W);

    // ---- Stage 1: raw rows [ybase, ybase+nrows) -> F4 rows [0, nrows) ----
    auto stage_raw = [&](int ybase, int nrows) {
        const int iters = (nrows * 16) >> 9;   // 64 rows -> 2, 32 rows -> 1
        const bool interior = (x0 >= 0) && (x0 + 64 <= W) &&
                              (ybase >= 0) && (ybase + nrows <= H);
        if (interior) {
            for (int it = 0; it < iters; ++it) {
                int idx = it * 512 + tid;
                int ry = idx >> 4, f4 = idx & 15;
                int rl = ry & 7, pf = ry & 1;
                const float* ip = Ib + (ybase + ry) * W + x0 + 4 * f4;
                const float* pp = Pb + (ybase + ry) * W + x0 + 4 * f4;
                float4 iv = *(const float4*)ip;
                float4 pv = *(const float4*)pp;
                float2 e0 = make_float2(iv.x, pv.x), e1 = make_float2(iv.y, pv.y);
                float2 e2 = make_float2(iv.z, pv.z), e3 = make_float2(iv.w, pv.w);
                float2 a0 = pf ? e1 : e0, a1 = pf ? e0 : e1;
                float2 b0 = pf ? e3 : e2, b1 = pf ? e2 : e3;
                float4* Fr = &F4[ry * 32];
                Fr[(2 * f4) ^ rl]     = make_float4(a0.x, a0.y, a1.x, a1.y);
                Fr[(2 * f4 + 1) ^ rl] = make_float4(b0.x, b0.y, b1.x, b1.y);
            }
        } else {
            for (int it = 0; it < iters; ++it) {
                int idx = it * 512 + tid;
                int ry = idx >> 4, f4 = idx & 15;
                int rl = ry & 7, pf = ry & 1;
                int gy = ybase + ry;
                float2 el[4];
                #pragma unroll
                for (int k = 0; k < 4; ++k) {
                    int gx = x0 + 4 * f4 + k;
                    bool v = ((unsigned)gy < (unsigned)H) && ((unsigned)gx < (unsigned)W);
                    el[k].x = v ? Ib[gy * W + gx] : 0.f;
                    el[k].y = v ? Pb[gy * W + gx] : 0.f;
                }
                float2 a0 = pf ? el[1] : el[0], a1 = pf ? el[0] : el[1];
                float2 b0 = pf ? el[3] : el[2], b1 = pf ? el[2] : el[3];
                float4* Fr = &F4[ry * 32];
                Fr[(2 * f4) ^ rl]     = make_float4(a0.x, a0.y, a1.x, a1.y);
                Fr[(2 * f4 + 1) ^ rl] = make_float4(b0.x, b0.y, b1.x, b1.y);
            }
        }
    };

    // ---- Stage 2: horizontal 17-sums of staged rows -> H ring ----
    // full: 512 thr, 64 rows.  half: 256 thr, 32 rows.  Ring slot = (tbase+r)&63.
    auto s2_rows = [&](int tbase, bool full) {
        if (full || tid < 256) {
            const int r  = tid >> 3, e = tid & 7;
            const int rl = r & 7, pf = r & 1;
            const int c0 = 6 * e;
            const float4* Fr = &F4[r * 32];
            const float2* Er = (const float2*)Fr;
            float4 S = make_float4(0.f, 0.f, 0.f, 0.f);
            const int gb = 3 * e;
            #pragma unroll
            for (int m = 0; m < 8; ++m) {   // elements c0 .. c0+15
                float4 fr = Fr[(gb + m) ^ rl];
                S.x += fr.x + fr.z;
                S.y += fr.y + fr.w;
                S.z += fr.x * fr.y + fr.z * fr.w;
                S.w += fr.x * fr.x + fr.z * fr.z;
            }
            {
                int c = c0 + 16;            // even -> within-granule slot = pf
                float2 v = Er[(((c >> 1) ^ rl) << 1) | pf];
                S.x += v.x; S.y += v.y; S.z += v.x * v.y; S.w += v.x * v.x;
            }
            const int slot = (tbase + r) & 63;   // slot&7 == r&7 (tbase % 32 == 0)
            float4* Hrow = &H4[slot * 48];
            #pragma unroll
            for (int k = 0; k < 6; ++k) {
                Hrow[(c0 + k) ^ rl] = S;
                if (k < 5) {
                    int ca = c0 + k + 17, cs = c0 + k;
                    float2 va = Er[(((ca >> 1) ^ rl) << 1) | ((ca & 1) ^ pf)];
                    float2 vs = Er[(((cs >> 1) ^ rl) << 1) | ((cs & 1) ^ pf)];
                    S.x += va.x - vs.x;
                    S.y += va.y - vs.y;
                    S.z += va.x * va.y - vs.x * vs.y;
                    S.w += va.x * va.x - vs.x * vs.x;
                }
            }
        }
    };

    // ---- Stage 3: vertical 17-sums over H ring rows [32g, 32g+48) -> a,b ----
    auto s3g = [&](int g) {
        if (tid < 384) {
            const int col = tid % 48, chunk = tid / 48;
            const int cy0 = chunk * 6;
            const int tb = 32 * g;
            float4 S = make_float4(0.f, 0.f, 0.f, 0.f);
            #pragma unroll
            for (int j = 0; j < 17; ++j) {
                int row = tb + cy0 + j;
                float4 v = H4[(row & 63) * 48 + (col ^ (row & 7))];
                S.x += v.x; S.y += v.y; S.z += v.z; S.w += v.w;
            }
            int gx = x0 + RAD + col;
            int nx = min(gx + RAD, W - 1) - max(gx - RAD, 0) + 1;
            #pragma unroll
            for (int k = 0; k < 6; ++k) {
                int cy = cy0 + k;
                int gy = Y0 + 32 * g - RAD + cy;
                float a = 0.f, b = 0.f;
                if (((unsigned)gy < (unsigned)H) && ((unsigned)gx < (unsigned)W)) {
                    int ny = min(gy + RAD, H - 1) - max(gy - RAD, 0) + 1;
                    float invN = __builtin_amdgcn_rcpf((float)(nx * ny));
                    float mI = S.x * invN, mp = S.y * invN;
                    float cov = S.z * invN - mI * mp;
                    float var = S.w * invN - mI * mI;
                    a = cov * __builtin_amdgcn_rcpf(var + EPS);
                    b = mp - a * mI;
                }
                AB[cy * 50 + col] = make_float2(a, b);
                if (k < 5) {
                    int ra = tb + cy + 17, rs = tb + cy;
                    float4 va = H4[(ra & 63) * 48 + (col ^ (ra & 7))];
                    float4 vs = H4[(rs & 63) * 48 + (col ^ (rs & 7))];
                    S.x += va.x - vs.x; S.y += va.y - vs.y;
                    S.z += va.z - vs.z; S.w += va.w - vs.w;
                }
            }
        }
    };

    // ---- Stage 4: horizontal 17-sums of a,b -> HAB ----
    auto s4 = [&]() {
        if (tid < 384) {
            const int r = tid % 48, e = tid / 48;   // e in 0..7, 4 output cols each
            const int c0 = 4 * e;
            const float2* row  = &AB[r * 50];
            const float4* rowg = (const float4*)row;   // rows 16B-aligned
            float2 S = make_float2(0.f, 0.f);
            #pragma unroll
            for (int m = 0; m < 8; ++m) {           // elements c0 .. c0+15
                float4 gq = rowg[2 * e + m];
                S.x += gq.x + gq.z;
                S.y += gq.y + gq.w;
            }
            {
                float2 v = row[c0 + 16];
                S.x += v.x; S.y += v.y;
            }
            #pragma unroll
            for (int k = 0; k < 4; ++k) {
                HAB[r * 33 + c0 + k] = S;
                if (k < 3) {
                    float2 va = row[c0 + k + 17];
                    float2 vs = row[c0 + k];
                    S.x += va.x - vs.x; S.y += va.y - vs.y;
                }
            }
        }
    };

    // ---- Stage 5: vertical 17-sums of HAB -> q for group g ----
    auto s5g = [&](int g) {
        const int col = tid & 31, chunk = tid >> 5;   // 16 chunks x 2 rows
        const int oy0 = chunk * 2;
        float2 S = make_float2(0.f, 0.f);
        #pragma unroll
        for (int j = 0; j < 17; ++j) {
            float2 v = HAB[(oy0 + j) * 33 + col];
            S.x += v.x; S.y += v.y;
        }
        int gx = x0 + 2 * RAD + col;
        int nx = min(gx + RAD, W - 1) - max(gx - RAD, 0) + 1;
        #pragma unroll
        for (int k = 0; k < 2; ++k) {
            int oy = oy0 + k;
            int gy = Y0 + 32 * g + oy;
            int ny = min(gy + RAD, H - 1) - max(gy - RAD, 0) + 1;
            float invN = __builtin_amdgcn_rcpf((float)(nx * ny));
            float iv = Ib[gy * W + gx];
            Ob[gy * W + gx] = S.x * invN * iv + S.y * invN;
            if (k < 1) {
                float2 va = HAB[(oy + 17) * 33 + col];
                float2 vs = HAB[oy * 33 + col];
                S.x += va.x - vs.x; S.y += va.y - vs.y;
            }
        }
    };

    // ---- Chained schedule ----
    stage_raw(Y0 - 2 * RAD, 64);          // raw rows t in [0,64)
    __syncthreads();
    s2_rows(0, true);                     // H ring slots 0..63
    #pragma unroll 1
    for (int g = 0; g < KCH; ++g) {
        __syncthreads();
        s3g(g);                           // H[32g..32g+48) -> AB (in F4 space)
        __syncthreads();
        s4();                             // AB -> HAB
        __syncthreads();
        if (g < KCH - 1)
            stage_raw(Y0 + 32 * g + 48, 32);   // next raw t in [32g+64,32g+96)
        s5g(g);                           // HAB -> out (overlaps staging loads)
        if (g < KCH - 1) {
            __syncthreads();
            s2_rows(32 * g + 64, false);  // append 32 H rows to ring
        }
    }
}

extern "C" void kernel_launch(void* const* d_in, const int* in_sizes, int n_in,
                              void* d_out, int out_size, void* d_ws, size_t ws_size,
                              hipStream_t stream) {
    const float* I = (const float*)d_in[0];
    const float* P = (const float*)d_in[1];
    float* out = (float*)d_out;
    int planes = in_sizes[0] / (H * W);   // 48
    dim3 grid(W / TILE, H / (TILE * KCH), planes);
    guided_filter_kernel<<<grid, dim3(512), 0, stream>>>(I, P, out);
}